// Round 1
// baseline (14240.302 us; speedup 1.0000x reference)
//
#include <hip/hip_runtime.h>
#include <math.h>

#define NN 50000
#define NE 800000
#define DIN 32
#define D 128
#define NL 3
#define NG 64
#define LN_EPS 1e-5f

__device__ __forceinline__ float gelu_f(float x) {
    return 0.5f * x * (1.0f + erff(x * 0.70710678118654752f));
}

__device__ __forceinline__ void fma4(float4& acc, float x, float4 w) {
    acc.x = fmaf(x, w.x, acc.x);
    acc.y = fmaf(x, w.y, acc.y);
    acc.z = fmaf(x, w.z, acc.z);
    acc.w = fmaf(x, w.w, acc.w);
}

// hidden = gelu(X @ W_in + b_in) : (N,32) @ (32,128)
__global__ __launch_bounds__(256) void input_proj_kernel(
    const float* __restrict__ X, const float* __restrict__ W,
    const float* __restrict__ b, float* __restrict__ hidden)
{
    __shared__ float sW[DIN * D];  // 16 KB
    for (int i = threadIdx.x; i < DIN * D; i += 256) sW[i] = W[i];
    __syncthreads();
    int o = blockIdx.x * 256 + threadIdx.x;   // grid covers exactly N*D
    int n = o >> 7, d = o & 127;
    const float* x = X + n * DIN;
    float acc = b[d];
#pragma unroll
    for (int k = 0; k < DIN; ++k) acc = fmaf(x[k], sW[k * D + d], acc);
    hidden[o] = gelu_f(acc);
}

// Fused edge MLP + scatter-add. 8 edges per 256-thread block.
// msg = gelu([h[src], h[dst], ew] @ W1 + b1) @ W2 + b2 ; agg[dst] += msg
__global__ __launch_bounds__(256) void edge_kernel(
    const float* __restrict__ hidden, const int* __restrict__ src,
    const int* __restrict__ dst, const float* __restrict__ ew,
    const float* __restrict__ W1, const float* __restrict__ b1,
    const float* __restrict__ W2, const float* __restrict__ b2,
    float* __restrict__ agg)
{
    __shared__ float s_in[8 * 264];   // 257 used, padded to 264 for 16B-aligned rows
    __shared__ float s_h1[8 * 128];
    __shared__ int   s_dst[8];
    const int tid = threadIdx.x;
    const int e0 = blockIdx.x * 8;

    if (tid < 8) s_dst[tid] = dst[e0 + tid];
    for (int i = tid; i < 8 * 257; i += 256) {
        int e = i / 257;
        int k = i - e * 257;
        int edge = e0 + e;
        float v;
        if (k < 128)      v = hidden[(size_t)src[edge] * D + k];
        else if (k < 256) v = hidden[(size_t)dst[edge] * D + (k - 128)];
        else              v = ew[edge];
        s_in[e * 264 + k] = v;
    }
    __syncthreads();

    const int e = tid >> 5;        // edge within block (0..7)
    const int dg = tid & 31;       // float4 column group (0..31)
    const float* in = s_in + e * 264;

    // h1 = gelu(in @ W1 + b1), thread owns columns dg*4..dg*4+3
    float4 acc = *(const float4*)(b1 + dg * 4);
#pragma unroll 4
    for (int k = 0; k < 256; k += 4) {
        float4 x4 = *(const float4*)(in + k);
        float4 w0 = *(const float4*)(W1 + (size_t)(k + 0) * D + dg * 4);
        float4 w1 = *(const float4*)(W1 + (size_t)(k + 1) * D + dg * 4);
        float4 w2 = *(const float4*)(W1 + (size_t)(k + 2) * D + dg * 4);
        float4 w3 = *(const float4*)(W1 + (size_t)(k + 3) * D + dg * 4);
        fma4(acc, x4.x, w0);
        fma4(acc, x4.y, w1);
        fma4(acc, x4.z, w2);
        fma4(acc, x4.w, w3);
    }
    {   // k = 256 (edge-weight row)
        float x = in[256];
        float4 wl = *(const float4*)(W1 + (size_t)256 * D + dg * 4);
        fma4(acc, x, wl);
    }
    float* h1p = s_h1 + e * 128 + dg * 4;
    h1p[0] = gelu_f(acc.x);
    h1p[1] = gelu_f(acc.y);
    h1p[2] = gelu_f(acc.z);
    h1p[3] = gelu_f(acc.w);
    __syncthreads();

    // msg = h1 @ W2 + b2
    const float* h1 = s_h1 + e * 128;
    float4 acc2 = *(const float4*)(b2 + dg * 4);
#pragma unroll 4
    for (int k = 0; k < 128; k += 4) {
        float4 x4 = *(const float4*)(h1 + k);
        float4 w0 = *(const float4*)(W2 + (size_t)(k + 0) * D + dg * 4);
        float4 w1 = *(const float4*)(W2 + (size_t)(k + 1) * D + dg * 4);
        float4 w2 = *(const float4*)(W2 + (size_t)(k + 2) * D + dg * 4);
        float4 w3 = *(const float4*)(W2 + (size_t)(k + 3) * D + dg * 4);
        fma4(acc2, x4.x, w0);
        fma4(acc2, x4.y, w1);
        fma4(acc2, x4.z, w2);
        fma4(acc2, x4.w, w3);
    }
    float* ap = agg + (size_t)s_dst[e] * D + dg * 4;
    atomicAdd(ap + 0, acc2.x);
    atomicAdd(ap + 1, acc2.y);
    atomicAdd(ap + 2, acc2.z);
    atomicAdd(ap + 3, acc2.w);
}

// Fused node update: u = gelu([h, agg] @ W1 + b1) @ W2 + b2;
// out = layer_norm(h + u) * gamma + beta.  8 nodes per 256-thread block.
__global__ __launch_bounds__(256) void node_kernel(
    const float* __restrict__ hidden, const float* __restrict__ agg,
    const float* __restrict__ W1, const float* __restrict__ b1,
    const float* __restrict__ W2, const float* __restrict__ b2,
    const float* __restrict__ gamma, const float* __restrict__ beta,
    float* __restrict__ out)
{
    __shared__ float s_cat[8 * 256];
    __shared__ float s_h1[8 * 128];
    const int tid = threadIdx.x;
    const int n0 = blockIdx.x * 8;

    for (int i = tid; i < 8 * 256; i += 256) {
        int e = i >> 8;
        int k = i & 255;
        size_t n = (size_t)(n0 + e);
        s_cat[i] = (k < 128) ? hidden[n * D + k] : agg[n * D + (k - 128)];
    }
    __syncthreads();

    const int e = tid >> 5;
    const int dg = tid & 31;
    const size_t n = (size_t)(n0 + e);
    const float* in = s_cat + e * 256;

    float4 acc = *(const float4*)(b1 + dg * 4);
#pragma unroll 4
    for (int k = 0; k < 256; k += 4) {
        float4 x4 = *(const float4*)(in + k);
        float4 w0 = *(const float4*)(W1 + (size_t)(k + 0) * D + dg * 4);
        float4 w1 = *(const float4*)(W1 + (size_t)(k + 1) * D + dg * 4);
        float4 w2 = *(const float4*)(W1 + (size_t)(k + 2) * D + dg * 4);
        float4 w3 = *(const float4*)(W1 + (size_t)(k + 3) * D + dg * 4);
        fma4(acc, x4.x, w0);
        fma4(acc, x4.y, w1);
        fma4(acc, x4.z, w2);
        fma4(acc, x4.w, w3);
    }
    float* h1p = s_h1 + e * 128 + dg * 4;
    h1p[0] = gelu_f(acc.x);
    h1p[1] = gelu_f(acc.y);
    h1p[2] = gelu_f(acc.z);
    h1p[3] = gelu_f(acc.w);
    __syncthreads();

    const float* h1 = s_h1 + e * 128;
    float4 acc2 = *(const float4*)(b2 + dg * 4);
#pragma unroll 4
    for (int k = 0; k < 128; k += 4) {
        float4 x4 = *(const float4*)(h1 + k);
        float4 w0 = *(const float4*)(W2 + (size_t)(k + 0) * D + dg * 4);
        float4 w1 = *(const float4*)(W2 + (size_t)(k + 1) * D + dg * 4);
        float4 w2 = *(const float4*)(W2 + (size_t)(k + 2) * D + dg * 4);
        float4 w3 = *(const float4*)(W2 + (size_t)(k + 3) * D + dg * 4);
        fma4(acc2, x4.x, w0);
        fma4(acc2, x4.y, w1);
        fma4(acc2, x4.z, w2);
        fma4(acc2, x4.w, w3);
    }

    // residual + layernorm over 128 elems; each node = one 32-lane half-wave
    float4 h = *(const float4*)(hidden + n * D + dg * 4);
    float4 r;
    r.x = h.x + acc2.x;
    r.y = h.y + acc2.y;
    r.z = h.z + acc2.z;
    r.w = h.w + acc2.w;
    float s1 = r.x + r.y + r.z + r.w;
    float s2 = r.x * r.x + r.y * r.y + r.z * r.z + r.w * r.w;
#pragma unroll
    for (int m = 16; m >= 1; m >>= 1) {
        s1 += __shfl_xor(s1, m);
        s2 += __shfl_xor(s2, m);
    }
    float mean = s1 * (1.0f / 128.0f);
    float var = s2 * (1.0f / 128.0f) - mean * mean;
    float rs = rsqrtf(var + LN_EPS);
    float4 g = *(const float4*)(gamma + dg * 4);
    float4 bb = *(const float4*)(beta + dg * 4);
    float4 o;
    o.x = (r.x - mean) * rs * g.x + bb.x;
    o.y = (r.y - mean) * rs * g.y + bb.y;
    o.z = (r.z - mean) * rs * g.z + bb.z;
    o.w = (r.w - mean) * rs * g.w + bb.w;
    *(float4*)(out + n * D + dg * 4) = o;
}

__global__ __launch_bounds__(256) void count_kernel(
    const int* __restrict__ batch, float* __restrict__ counts)
{
    int n = blockIdx.x * 256 + threadIdx.x;
    if (n < NN) atomicAdd(&counts[batch[n]], 1.0f);
}

__global__ __launch_bounds__(256) void pool_accum_kernel(
    const float* __restrict__ hidden, const int* __restrict__ batch,
    float* __restrict__ pooled)
{
    int o = blockIdx.x * 256 + threadIdx.x;   // grid covers exactly N*D
    int n = o >> 7, d = o & 127;
    atomicAdd(&pooled[(size_t)batch[n] * D + d], hidden[o]);
}

__global__ __launch_bounds__(256) void pool_div_kernel(
    float* __restrict__ pooled, const float* __restrict__ counts)
{
    int i = blockIdx.x * 256 + threadIdx.x;   // grid covers exactly G*D
    pooled[i] /= fmaxf(counts[i >> 7], 1.0f);
}

extern "C" void kernel_launch(void* const* d_in, const int* in_sizes, int n_in,
                              void* d_out, int out_size, void* d_ws, size_t ws_size,
                              hipStream_t stream) {
    const float* X     = (const float*)d_in[0];
    const int*   eidx  = (const int*)d_in[1];
    const float* ew    = (const float*)d_in[2];
    const int*   batch = (const int*)d_in[3];
    const float* W_in  = (const float*)d_in[5];
    const float* b_in  = (const float*)d_in[6];
    const float* eW1   = (const float*)d_in[7];
    const float* eb1   = (const float*)d_in[8];
    const float* eW2   = (const float*)d_in[9];
    const float* eb2   = (const float*)d_in[10];
    const float* uW1   = (const float*)d_in[11];
    const float* ub1   = (const float*)d_in[12];
    const float* uW2   = (const float*)d_in[13];
    const float* ub2   = (const float*)d_in[14];
    const float* gamma = (const float*)d_in[15];
    const float* beta  = (const float*)d_in[16];

    float* out_hidden = (float*)d_out;
    float* out_pooled = out_hidden + (size_t)NN * D;

    float* hA     = (float*)d_ws;
    float* hB     = hA + (size_t)NN * D;
    float* agg    = hB + (size_t)NN * D;
    float* counts = agg + (size_t)NN * D;

    const int* src = eidx;
    const int* dst = eidx + NE;

    input_proj_kernel<<<(NN * D) / 256, 256, 0, stream>>>(X, W_in, b_in, hA);

    float* bufs[2] = {hA, hB};
    float* hin = hA;
    for (int l = 0; l < NL; ++l) {
        hipMemsetAsync(agg, 0, (size_t)NN * D * sizeof(float), stream);
        edge_kernel<<<NE / 8, 256, 0, stream>>>(
            hin, src, dst, ew,
            eW1 + (size_t)l * 257 * D, eb1 + (size_t)l * D,
            eW2 + (size_t)l * D * D,   eb2 + (size_t)l * D, agg);
        float* hout = (l == NL - 1) ? out_hidden : bufs[(l + 1) & 1];
        node_kernel<<<NN / 8, 256, 0, stream>>>(
            hin, agg,
            uW1 + (size_t)l * 2 * D * D, ub1 + (size_t)l * D,
            uW2 + (size_t)l * D * D,     ub2 + (size_t)l * D,
            gamma + (size_t)l * D, beta + (size_t)l * D, hout);
        hin = hout;
    }

    hipMemsetAsync(out_pooled, 0, (size_t)NG * D * sizeof(float), stream);
    hipMemsetAsync(counts, 0, (size_t)NG * sizeof(float), stream);
    count_kernel<<<(NN + 255) / 256, 256, 0, stream>>>(batch, counts);
    pool_accum_kernel<<<(NN * D) / 256, 256, 0, stream>>>(out_hidden, batch, out_pooled);
    pool_div_kernel<<<(NG * D) / 256, 256, 0, stream>>>(out_pooled, counts);
}

// Round 2
// 1587.741 us; speedup vs baseline: 8.9689x; 8.9689x over previous
//
#include <hip/hip_runtime.h>
#include <math.h>

#define NN 50000
#define NE 800000
#define DIN 32
#define D 128
#define NL 3
#define NG 64
#define LN_EPS 1e-5f

typedef unsigned short u16;
typedef __bf16 bf16x8 __attribute__((ext_vector_type(8)));
typedef float f32x4 __attribute__((ext_vector_type(4)));

__device__ __forceinline__ float gelu_f(float x) {
    return 0.5f * x * (1.0f + erff(x * 0.70710678118654752f));
}

// fp32 -> bf16 RNE
__device__ __forceinline__ u16 f2bf(float x) {
    unsigned int u = __float_as_uint(x);
    u += 0x7fffu + ((u >> 16) & 1u);
    return (u16)(u >> 16);
}

// hidden = gelu(X @ W_in + b_in); also emit bf16 copy
__global__ __launch_bounds__(256) void input_proj_kernel(
    const float* __restrict__ X, const float* __restrict__ W,
    const float* __restrict__ b, float* __restrict__ hidden, u16* __restrict__ hbf)
{
    __shared__ float sW[DIN * D];
    for (int i = threadIdx.x; i < DIN * D; i += 256) sW[i] = W[i];
    __syncthreads();
    int o = blockIdx.x * 256 + threadIdx.x;   // grid covers exactly N*D
    int n = o >> 7, d = o & 127;
    const float* x = X + n * DIN;
    float acc = b[d];
#pragma unroll
    for (int k = 0; k < DIN; ++k) acc = fmaf(x[k], sW[k * D + d], acc);
    float g = gelu_f(acc);
    hidden[o] = g;
    hbf[o] = f2bf(g);
}

// dst[l][n][k] = bf16(src[l][k][n])  (build N-major transposed bf16 weights)
__global__ __launch_bounds__(256) void transpose_cvt_kernel(
    const float* __restrict__ src, u16* __restrict__ dst,
    int K, int N, int srcLS, int dstLS)
{
    int i = blockIdx.x * 256 + threadIdx.x;   // grid covers NL*K*N exactly
    int per = K * N;
    int l = i / per;
    int r = i - l * per;
    int n = r / K;
    int k = r - n * K;
    dst[(size_t)l * dstLS + n * K + k] = f2bf(src[(size_t)l * srcLS + k * N + n]);
}

// Edge MLP on MFMA. 64 edges/block, 4 waves split the 128 output cols.
// msg = gelu([hs,hd]@W1[0:256] + ew*W1[256] + b1) @ W2 + b2 ; agg[dst] += msg
__global__ __launch_bounds__(256, 3) void edge_mfma_kernel(
    const u16* __restrict__ hbf, const int* __restrict__ srcI, const int* __restrict__ dstI,
    const float* __restrict__ ew,
    const u16* __restrict__ W1T, const float* __restrict__ W1last, const float* __restrict__ b1,
    const u16* __restrict__ W2T, const float* __restrict__ b2,
    float* __restrict__ agg)
{
    __shared__ u16 sA[64 * 264];    // 64 edges x 256 k, +8 pad
    __shared__ u16 sH1[64 * 136];   // 64 x 128, +8 pad
    __shared__ float s_ew[64];
    __shared__ int s_dst[64];
    const int tid = threadIdx.x;
    const int e0 = blockIdx.x * 64;

    if (tid < 64) { s_ew[tid] = ew[e0 + tid]; s_dst[tid] = dstI[e0 + tid]; }
    {
        const int e = tid >> 2, q = tid & 3;      // 4 threads per edge
        const int edge = e0 + e;
        const uint4* hs = (const uint4*)(hbf + (size_t)srcI[edge] * D);
        const uint4* hd = (const uint4*)(hbf + (size_t)dstI[edge] * D);
        uint4* ar = (uint4*)(sA + e * 264);
#pragma unroll
        for (int c = 0; c < 8; ++c) {
            int cc = q * 8 + c;                   // 16B chunk index 0..31
            ar[cc] = (cc < 16) ? hs[cc] : hd[cc - 16];
        }
    }
    __syncthreads();

    const int lane = tid & 63;
    const int l15 = lane & 15;
    const int quad = lane >> 4;
    const int nbase = (tid >> 6) * 32;

    f32x4 acc[4][2];
#pragma unroll
    for (int mt = 0; mt < 4; ++mt)
#pragma unroll
        for (int nt = 0; nt < 2; ++nt) acc[mt][nt] = (f32x4){0.f, 0.f, 0.f, 0.f};

    const u16* bp0 = W1T + (size_t)(nbase + l15) * 256 + quad * 8;
    const u16* bp1 = bp0 + 16 * 256;
#pragma unroll
    for (int kb = 0; kb < 256; kb += 32) {
        bf16x8 bf0 = *(const bf16x8*)(bp0 + kb);
        bf16x8 bf1 = *(const bf16x8*)(bp1 + kb);
#pragma unroll
        for (int mt = 0; mt < 4; ++mt) {
            bf16x8 af = *(const bf16x8*)(sA + (mt * 16 + l15) * 264 + quad * 8 + kb);
            acc[mt][0] = __builtin_amdgcn_mfma_f32_16x16x32_bf16(af, bf0, acc[mt][0], 0, 0, 0);
            acc[mt][1] = __builtin_amdgcn_mfma_f32_16x16x32_bf16(af, bf1, acc[mt][1], 0, 0, 0);
        }
    }

    // epilogue 1: + b1 + ew*W1[256]; gelu; -> sH1 (bf16, A-layout for GEMM2)
#pragma unroll
    for (int mt = 0; mt < 4; ++mt)
#pragma unroll
        for (int nt = 0; nt < 2; ++nt) {
            const int col = nbase + nt * 16 + l15;
            const float w1l = W1last[col];
            const float bb = b1[col];
#pragma unroll
            for (int r = 0; r < 4; ++r) {
                const int row = mt * 16 + quad * 4 + r;
                float v = acc[mt][nt][r] + bb + s_ew[row] * w1l;
                sH1[row * 136 + col] = f2bf(gelu_f(v));
            }
        }
    __syncthreads();

    f32x4 acc2[4][2];
#pragma unroll
    for (int mt = 0; mt < 4; ++mt)
#pragma unroll
        for (int nt = 0; nt < 2; ++nt) acc2[mt][nt] = (f32x4){0.f, 0.f, 0.f, 0.f};

    const u16* cp0 = W2T + (size_t)(nbase + l15) * 128 + quad * 8;
    const u16* cp1 = cp0 + 16 * 128;
#pragma unroll
    for (int kb = 0; kb < 128; kb += 32) {
        bf16x8 bf0 = *(const bf16x8*)(cp0 + kb);
        bf16x8 bf1 = *(const bf16x8*)(cp1 + kb);
#pragma unroll
        for (int mt = 0; mt < 4; ++mt) {
            bf16x8 af = *(const bf16x8*)(sH1 + (mt * 16 + l15) * 136 + quad * 8 + kb);
            acc2[mt][0] = __builtin_amdgcn_mfma_f32_16x16x32_bf16(af, bf0, acc2[mt][0], 0, 0, 0);
            acc2[mt][1] = __builtin_amdgcn_mfma_f32_16x16x32_bf16(af, bf1, acc2[mt][1], 0, 0, 0);
        }
    }

#pragma unroll
    for (int mt = 0; mt < 4; ++mt)
#pragma unroll
        for (int nt = 0; nt < 2; ++nt) {
            const int col = nbase + nt * 16 + l15;
            const float bb = b2[col];
#pragma unroll
            for (int r = 0; r < 4; ++r) {
                const int row = mt * 16 + quad * 4 + r;
                atomicAdd(&agg[(size_t)s_dst[row] * D + col], acc2[mt][nt][r] + bb);
            }
        }
}

// Node update on MFMA + residual + LayerNorm. 64 nodes/block.
__global__ __launch_bounds__(256, 3) void node_mfma_kernel(
    const float* __restrict__ hidden, const u16* __restrict__ hbf,
    const float* __restrict__ agg,
    const u16* __restrict__ W1T, const float* __restrict__ b1,
    const u16* __restrict__ W2T, const float* __restrict__ b2,
    const float* __restrict__ gamma, const float* __restrict__ beta,
    float* __restrict__ hidden_out, u16* __restrict__ hbf_out)
{
    __shared__ u16 sA[64 * 264];
    __shared__ u16 sH1[64 * 136];
    float* sR = (float*)sA;        // reuse as 64 x 132 fp32 after GEMM1
    const int tid = threadIdx.x;
    const int n0 = blockIdx.x * 64;

    {
        const int e = tid >> 2, q = tid & 3;
        int n = n0 + e; if (n >= NN) n = NN - 1;
        const uint4* hs = (const uint4*)(hbf + (size_t)n * D);
        const float4* ag = (const float4*)(agg + (size_t)n * D);
        uint4* ar = (uint4*)(sA + e * 264);
#pragma unroll
        for (int c = 0; c < 8; ++c) {
            int cc = q * 8 + c;
            if (cc < 16) ar[cc] = hs[cc];
            else {
                float4 x0 = ag[(cc - 16) * 2];
                float4 x1 = ag[(cc - 16) * 2 + 1];
                uint4 p;
                p.x = (unsigned)f2bf(x0.x) | ((unsigned)f2bf(x0.y) << 16);
                p.y = (unsigned)f2bf(x0.z) | ((unsigned)f2bf(x0.w) << 16);
                p.z = (unsigned)f2bf(x1.x) | ((unsigned)f2bf(x1.y) << 16);
                p.w = (unsigned)f2bf(x1.z) | ((unsigned)f2bf(x1.w) << 16);
                ar[cc] = p;
            }
        }
    }
    __syncthreads();

    const int lane = tid & 63;
    const int l15 = lane & 15;
    const int quad = lane >> 4;
    const int nbase = (tid >> 6) * 32;

    f32x4 acc[4][2];
#pragma unroll
    for (int mt = 0; mt < 4; ++mt)
#pragma unroll
        for (int nt = 0; nt < 2; ++nt) acc[mt][nt] = (f32x4){0.f, 0.f, 0.f, 0.f};

    const u16* bp0 = W1T + (size_t)(nbase + l15) * 256 + quad * 8;
    const u16* bp1 = bp0 + 16 * 256;
#pragma unroll
    for (int kb = 0; kb < 256; kb += 32) {
        bf16x8 bf0 = *(const bf16x8*)(bp0 + kb);
        bf16x8 bf1 = *(const bf16x8*)(bp1 + kb);
#pragma unroll
        for (int mt = 0; mt < 4; ++mt) {
            bf16x8 af = *(const bf16x8*)(sA + (mt * 16 + l15) * 264 + quad * 8 + kb);
            acc[mt][0] = __builtin_amdgcn_mfma_f32_16x16x32_bf16(af, bf0, acc[mt][0], 0, 0, 0);
            acc[mt][1] = __builtin_amdgcn_mfma_f32_16x16x32_bf16(af, bf1, acc[mt][1], 0, 0, 0);
        }
    }

#pragma unroll
    for (int mt = 0; mt < 4; ++mt)
#pragma unroll
        for (int nt = 0; nt < 2; ++nt) {
            const int col = nbase + nt * 16 + l15;
            const float bb = b1[col];
#pragma unroll
            for (int r = 0; r < 4; ++r) {
                const int row = mt * 16 + quad * 4 + r;
                sH1[row * 136 + col] = f2bf(gelu_f(acc[mt][nt][r] + bb));
            }
        }
    __syncthreads();   // also guarantees all sA reads done before sR overwrite

    f32x4 acc2[4][2];
#pragma unroll
    for (int mt = 0; mt < 4; ++mt)
#pragma unroll
        for (int nt = 0; nt < 2; ++nt) acc2[mt][nt] = (f32x4){0.f, 0.f, 0.f, 0.f};

    const u16* cp0 = W2T + (size_t)(nbase + l15) * 128 + quad * 8;
    const u16* cp1 = cp0 + 16 * 128;
#pragma unroll
    for (int kb = 0; kb < 128; kb += 32) {
        bf16x8 bf0 = *(const bf16x8*)(cp0 + kb);
        bf16x8 bf1 = *(const bf16x8*)(cp1 + kb);
#pragma unroll
        for (int mt = 0; mt < 4; ++mt) {
            bf16x8 af = *(const bf16x8*)(sH1 + (mt * 16 + l15) * 136 + quad * 8 + kb);
            acc2[mt][0] = __builtin_amdgcn_mfma_f32_16x16x32_bf16(af, bf0, acc2[mt][0], 0, 0, 0);
            acc2[mt][1] = __builtin_amdgcn_mfma_f32_16x16x32_bf16(af, bf1, acc2[mt][1], 0, 0, 0);
        }
    }

    // r = hidden + u -> sR (fp32)
#pragma unroll
    for (int mt = 0; mt < 4; ++mt)
#pragma unroll
        for (int nt = 0; nt < 2; ++nt) {
            const int col = nbase + nt * 16 + l15;
            const float bb = b2[col];
#pragma unroll
            for (int r = 0; r < 4; ++r) {
                const int row = mt * 16 + quad * 4 + r;
                int n = n0 + row; if (n >= NN) n = NN - 1;
                sR[row * 132 + col] = acc2[mt][nt][r] + bb + hidden[(size_t)n * D + col];
            }
        }
    __syncthreads();

    // LayerNorm: 4 threads per node, 32 elems each
    {
        const int e = tid >> 2, t4 = tid & 3;
        const int n = n0 + e;
        const float* rr = sR + e * 132 + t4 * 32;
        float s1 = 0.f, s2 = 0.f;
        float4 v[8];
#pragma unroll
        for (int i = 0; i < 8; ++i) {
            v[i] = *(const float4*)(rr + i * 4);
            s1 += v[i].x + v[i].y + v[i].z + v[i].w;
            s2 += v[i].x * v[i].x + v[i].y * v[i].y + v[i].z * v[i].z + v[i].w * v[i].w;
        }
        s1 += __shfl_xor(s1, 1); s2 += __shfl_xor(s2, 1);
        s1 += __shfl_xor(s1, 2); s2 += __shfl_xor(s2, 2);
        const float mean = s1 * (1.f / 128.f);
        const float var = s2 * (1.f / 128.f) - mean * mean;
        const float rs = rsqrtf(var + LN_EPS);
        if (n < NN) {
            float* op = hidden_out + (size_t)n * D + t4 * 32;
            u16* bp = hbf_out + (size_t)n * D + t4 * 32;
#pragma unroll
            for (int i = 0; i < 8; ++i) {
                const float4 g = *(const float4*)(gamma + t4 * 32 + i * 4);
                const float4 be = *(const float4*)(beta + t4 * 32 + i * 4);
                float4 o;
                o.x = (v[i].x - mean) * rs * g.x + be.x;
                o.y = (v[i].y - mean) * rs * g.y + be.y;
                o.z = (v[i].z - mean) * rs * g.z + be.z;
                o.w = (v[i].w - mean) * rs * g.w + be.w;
                *(float4*)(op + i * 4) = o;
                uint2 pk;
                pk.x = (unsigned)f2bf(o.x) | ((unsigned)f2bf(o.y) << 16);
                pk.y = (unsigned)f2bf(o.z) | ((unsigned)f2bf(o.w) << 16);
                *(uint2*)(bp + i * 4) = pk;
            }
        }
    }
}

// run-length count of sorted batch index
__global__ __launch_bounds__(256) void count_kernel(
    const int* __restrict__ batch, float* __restrict__ counts)
{
    int t = blockIdx.x * 256 + threadIdx.x;   // 32 blocks -> 8192 threads
    const int chunk = (NN + 8191) / 8192;
    int beg = t * chunk, end = beg + chunk;
    if (end > NN) end = NN;
    if (beg >= NN) return;
    int cur = batch[beg];
    float cnt = 0.f;
    for (int i = beg; i < end; ++i) {
        int b = batch[i];
        if (b != cur) { atomicAdd(&counts[cur], cnt); cur = b; cnt = 0.f; }
        cnt += 1.f;
    }
    atomicAdd(&counts[cur], cnt);
}

// run-length pooled sum (batch sorted): block = 128 nodes, thread = 1 col x 64 nodes
__global__ __launch_bounds__(256) void pool_accum_kernel(
    const float* __restrict__ hidden, const int* __restrict__ batch,
    float* __restrict__ pooled)
{
    __shared__ int sb[128];
    const int n0 = blockIdx.x * 128;
    const int tid = threadIdx.x;
    if (tid < 128) sb[tid] = (n0 + tid < NN) ? batch[n0 + tid] : -1;
    __syncthreads();
    const int col = tid & 127, half = tid >> 7;
    const int base = half * 64;
    int cur = sb[base];
    float acc = 0.f;
    for (int i = 0; i < 64; ++i) {
        int n = n0 + base + i;
        if (n >= NN) break;
        int b = sb[base + i];
        if (b != cur) { atomicAdd(&pooled[cur * D + col], acc); cur = b; acc = 0.f; }
        acc += hidden[(size_t)n * D + col];
    }
    if (cur >= 0 && acc != 0.f) atomicAdd(&pooled[cur * D + col], acc);
}

__global__ __launch_bounds__(256) void pool_div_kernel(
    float* __restrict__ pooled, const float* __restrict__ counts)
{
    int i = blockIdx.x * 256 + threadIdx.x;   // grid covers exactly G*D
    pooled[i] /= fmaxf(counts[i >> 7], 1.0f);
}

extern "C" void kernel_launch(void* const* d_in, const int* in_sizes, int n_in,
                              void* d_out, int out_size, void* d_ws, size_t ws_size,
                              hipStream_t stream) {
    const float* X     = (const float*)d_in[0];
    const int*   eidx  = (const int*)d_in[1];
    const float* ew    = (const float*)d_in[2];
    const int*   batch = (const int*)d_in[3];
    const float* W_in  = (const float*)d_in[5];
    const float* b_in  = (const float*)d_in[6];
    const float* eW1   = (const float*)d_in[7];
    const float* eb1   = (const float*)d_in[8];
    const float* eW2   = (const float*)d_in[9];
    const float* eb2   = (const float*)d_in[10];
    const float* uW1   = (const float*)d_in[11];
    const float* ub1   = (const float*)d_in[12];
    const float* uW2   = (const float*)d_in[13];
    const float* ub2   = (const float*)d_in[14];
    const float* gamma = (const float*)d_in[15];
    const float* beta  = (const float*)d_in[16];

    float* out_hidden = (float*)d_out;
    float* out_pooled = out_hidden + (size_t)NN * D;

    float* hA   = (float*)d_ws;
    float* agg  = hA + (size_t)NN * D;
    u16*   hbf  = (u16*)(agg + (size_t)NN * D);
    u16*   eW1T = hbf + (size_t)NN * D;
    u16*   eW2T = eW1T + (size_t)NL * 128 * 256;
    u16*   uW1T = eW2T + (size_t)NL * 128 * 128;
    u16*   uW2T = uW1T + (size_t)NL * 128 * 256;
    float* counts = (float*)(uW2T + (size_t)NL * 128 * 128);

    const int* src = eidx;
    const int* dst = eidx + NE;

    transpose_cvt_kernel<<<384, 256, 0, stream>>>(eW1, eW1T, 256, 128, 257 * 128, 128 * 256);
    transpose_cvt_kernel<<<192, 256, 0, stream>>>(eW2, eW2T, 128, 128, 128 * 128, 128 * 128);
    transpose_cvt_kernel<<<384, 256, 0, stream>>>(uW1, uW1T, 256, 128, 256 * 128, 128 * 256);
    transpose_cvt_kernel<<<192, 256, 0, stream>>>(uW2, uW2T, 128, 128, 128 * 128, 128 * 128);
    input_proj_kernel<<<(NN * D) / 256, 256, 0, stream>>>(X, W_in, b_in, hA, hbf);

    const float* hin = hA;
    for (int l = 0; l < NL; ++l) {
        hipMemsetAsync(agg, 0, (size_t)NN * D * sizeof(float), stream);
        edge_mfma_kernel<<<NE / 64, 256, 0, stream>>>(
            hbf, src, dst, ew,
            eW1T + (size_t)l * 128 * 256,
            eW1 + (size_t)l * 257 * 128 + 256 * 128,   // fp32 row k=256 of W1
            eb1 + (size_t)l * D,
            eW2T + (size_t)l * 128 * 128, eb2 + (size_t)l * D, agg);
        float* hout = (l & 1) ? hA : out_hidden;
        node_mfma_kernel<<<(NN + 63) / 64, 256, 0, stream>>>(
            hin, hbf, agg,
            uW1T + (size_t)l * 128 * 256, ub1 + (size_t)l * D,
            uW2T + (size_t)l * 128 * 128, ub2 + (size_t)l * D,
            gamma + (size_t)l * D, beta + (size_t)l * D,
            hout, hbf);
        hin = hout;
    }

    hipMemsetAsync(out_pooled, 0, (size_t)NG * D * sizeof(float), stream);
    hipMemsetAsync(counts, 0, (size_t)NG * sizeof(float), stream);
    count_kernel<<<32, 256, 0, stream>>>(batch, counts);
    pool_accum_kernel<<<(NN + 127) / 128, 256, 0, stream>>>(out_hidden, batch, out_pooled);
    pool_div_kernel<<<(NG * D) / 256, 256, 0, stream>>>(out_pooled, counts);
}

// Round 3
// 1243.442 us; speedup vs baseline: 11.4523x; 1.2769x over previous
//
#include <hip/hip_runtime.h>
#include <math.h>

#define NN 50000
#define NE 800000
#define DIN 32
#define D 128
#define NL 3
#define NG 64
#define LN_EPS 1e-5f

typedef unsigned short u16;
typedef __bf16 bf16x8 __attribute__((ext_vector_type(8)));
typedef float f32x4 __attribute__((ext_vector_type(4)));

__device__ __forceinline__ float gelu_f(float x) {
    return 0.5f * x * (1.0f + erff(x * 0.70710678118654752f));
}

// fp32 -> bf16 RNE
__device__ __forceinline__ u16 f2bf(float x) {
    unsigned int u = __float_as_uint(x);
    u += 0x7fffu + ((u >> 16) & 1u);
    return (u16)(u >> 16);
}

// ---------------- counting sort of edges by dst ----------------
__global__ __launch_bounds__(256) void hist_kernel(
    const int* __restrict__ dst, int* __restrict__ hist)
{
    int e = blockIdx.x * 256 + threadIdx.x;   // grid covers NE exactly
    atomicAdd(&hist[dst[e]], 1);
}

// exclusive scan over NN bins -> cursor (single 1024-thread block)
__global__ __launch_bounds__(1024) void scan_kernel(
    const int* __restrict__ hist, int* __restrict__ cursor)
{
    __shared__ int part[1024];
    const int t = threadIdx.x;
    const int CH = (NN + 1023) / 1024;        // 49
    int beg = t * CH, end = beg + CH;
    if (end > NN) end = NN;
    int s = 0;
    for (int i = beg; i < end; ++i) s += hist[i];
    part[t] = s;
    __syncthreads();
    for (int off = 1; off < 1024; off <<= 1) {
        int v = (t >= off) ? part[t - off] : 0;
        __syncthreads();
        part[t] += v;
        __syncthreads();
    }
    int run = (t > 0) ? part[t - 1] : 0;
    for (int i = beg; i < end; ++i) {
        cursor[i] = run;
        run += hist[i];
    }
}

__global__ __launch_bounds__(256) void scatter_kernel(
    const int* __restrict__ src, const int* __restrict__ dst,
    const float* __restrict__ ew, int* __restrict__ cursor,
    int* __restrict__ sSrc, int* __restrict__ sDst, float* __restrict__ sEw)
{
    int e = blockIdx.x * 256 + threadIdx.x;   // grid covers NE exactly
    int d = dst[e];
    int pos = atomicAdd(&cursor[d], 1);
    sSrc[pos] = src[e];
    sDst[pos] = d;
    sEw[pos] = ew[e];
}

// ---------------- projections / weight prep ----------------
__global__ __launch_bounds__(256) void input_proj_kernel(
    const float* __restrict__ X, const float* __restrict__ W,
    const float* __restrict__ b, float* __restrict__ hidden, u16* __restrict__ hbf)
{
    __shared__ float sW[DIN * D];
    for (int i = threadIdx.x; i < DIN * D; i += 256) sW[i] = W[i];
    __syncthreads();
    int o = blockIdx.x * 256 + threadIdx.x;   // grid covers exactly N*D
    int n = o >> 7, d = o & 127;
    const float* x = X + n * DIN;
    float acc = b[d];
#pragma unroll
    for (int k = 0; k < DIN; ++k) acc = fmaf(x[k], sW[k * D + d], acc);
    float g = gelu_f(acc);
    hidden[o] = g;
    hbf[o] = f2bf(g);
}

// dst[l][n][k] = bf16(src[l][k][n])
__global__ __launch_bounds__(256) void transpose_cvt_kernel(
    const float* __restrict__ src, u16* __restrict__ dst,
    int K, int N, int srcLS, int dstLS)
{
    int i = blockIdx.x * 256 + threadIdx.x;
    int per = K * N;
    int l = i / per;
    int r = i - l * per;
    int n = r / K;
    int k = r - n * K;
    dst[(size_t)l * dstLS + n * K + k] = f2bf(src[(size_t)l * srcLS + k * N + n]);
}

// ---------------- edge MLP (dst-sorted) + segment-combined scatter ----------------
__global__ __launch_bounds__(256, 3) void edge_mfma_kernel(
    const u16* __restrict__ hbf, const int* __restrict__ sSrc,
    const int* __restrict__ sDst, const float* __restrict__ sEw,
    const u16* __restrict__ W1T, const float* __restrict__ W1last, const float* __restrict__ b1,
    const u16* __restrict__ W2T, const float* __restrict__ b2,
    float* __restrict__ agg)
{
    __shared__ u16 sA[64 * 264];    // staging; later reused as fp32 msg 64x132
    __shared__ u16 sH1[64 * 136];
    __shared__ float s_ew[64];
    __shared__ int s_dst[64];
    const int tid = threadIdx.x;
    const int e0 = blockIdx.x * 64;

    if (tid < 64) { s_ew[tid] = sEw[e0 + tid]; s_dst[tid] = sDst[e0 + tid]; }
    {
        const int e = tid >> 2, q = tid & 3;
        const int edge = e0 + e;
        const uint4* hs = (const uint4*)(hbf + (size_t)sSrc[edge] * D);
        const uint4* hd = (const uint4*)(hbf + (size_t)sDst[edge] * D);
        uint4* ar = (uint4*)(sA + e * 264);
#pragma unroll
        for (int c = 0; c < 8; ++c) {
            int cc = q * 8 + c;
            ar[cc] = (cc < 16) ? hs[cc] : hd[cc - 16];
        }
    }
    __syncthreads();

    const int lane = tid & 63;
    const int l15 = lane & 15;
    const int quad = lane >> 4;
    const int nbase = (tid >> 6) * 32;

    f32x4 acc[4][2];
#pragma unroll
    for (int mt = 0; mt < 4; ++mt)
#pragma unroll
        for (int nt = 0; nt < 2; ++nt) acc[mt][nt] = (f32x4){0.f, 0.f, 0.f, 0.f};

    const u16* bp0 = W1T + (size_t)(nbase + l15) * 256 + quad * 8;
    const u16* bp1 = bp0 + 16 * 256;
#pragma unroll
    for (int kb = 0; kb < 256; kb += 32) {
        bf16x8 bf0 = *(const bf16x8*)(bp0 + kb);
        bf16x8 bf1 = *(const bf16x8*)(bp1 + kb);
#pragma unroll
        for (int mt = 0; mt < 4; ++mt) {
            bf16x8 af = *(const bf16x8*)(sA + (mt * 16 + l15) * 264 + quad * 8 + kb);
            acc[mt][0] = __builtin_amdgcn_mfma_f32_16x16x32_bf16(af, bf0, acc[mt][0], 0, 0, 0);
            acc[mt][1] = __builtin_amdgcn_mfma_f32_16x16x32_bf16(af, bf1, acc[mt][1], 0, 0, 0);
        }
    }

    // epilogue 1: + b1 + ew*W1[256]; gelu; -> sH1
#pragma unroll
    for (int mt = 0; mt < 4; ++mt)
#pragma unroll
        for (int nt = 0; nt < 2; ++nt) {
            const int col = nbase + nt * 16 + l15;
            const float w1l = W1last[col];
            const float bb = b1[col];
#pragma unroll
            for (int r = 0; r < 4; ++r) {
                const int row = mt * 16 + quad * 4 + r;
                float v = acc[mt][nt][r] + bb + s_ew[row] * w1l;
                sH1[row * 136 + col] = f2bf(gelu_f(v));
            }
        }
    __syncthreads();    // sH1 ready; sA reads done -> free for msg reuse

    f32x4 acc2[4][2];
#pragma unroll
    for (int mt = 0; mt < 4; ++mt)
#pragma unroll
        for (int nt = 0; nt < 2; ++nt) acc2[mt][nt] = (f32x4){0.f, 0.f, 0.f, 0.f};

    const u16* cp0 = W2T + (size_t)(nbase + l15) * 128 + quad * 8;
    const u16* cp1 = cp0 + 16 * 128;
#pragma unroll
    for (int kb = 0; kb < 128; kb += 32) {
        bf16x8 bf0 = *(const bf16x8*)(cp0 + kb);
        bf16x8 bf1 = *(const bf16x8*)(cp1 + kb);
#pragma unroll
        for (int mt = 0; mt < 4; ++mt) {
            bf16x8 af = *(const bf16x8*)(sH1 + (mt * 16 + l15) * 136 + quad * 8 + kb);
            acc2[mt][0] = __builtin_amdgcn_mfma_f32_16x16x32_bf16(af, bf0, acc2[mt][0], 0, 0, 0);
            acc2[mt][1] = __builtin_amdgcn_mfma_f32_16x16x32_bf16(af, bf1, acc2[mt][1], 0, 0, 0);
        }
    }

    // msg -> LDS fp32 (reuse sA: 64 rows x 132 floats)
    float* sMsg = (float*)sA;
#pragma unroll
    for (int mt = 0; mt < 4; ++mt)
#pragma unroll
        for (int nt = 0; nt < 2; ++nt) {
            const int col = nbase + nt * 16 + l15;
            const float bb = b2[col];
#pragma unroll
            for (int r = 0; r < 4; ++r) {
                const int row = mt * 16 + quad * 4 + r;
                sMsg[row * 132 + col] = acc2[mt][nt][r] + bb;
            }
        }
    __syncthreads();

    // segmented reduce over dst-sorted rows: one atomic per (segment, col)
    {
        const int col = tid & 127;
        const int rbase = (tid >> 7) * 32;
        int cur = s_dst[rbase];
        float a = 0.f;
        for (int i = 0; i < 32; ++i) {
            int d = s_dst[rbase + i];           // wave-uniform (broadcast)
            if (d != cur) {
                atomicAdd(&agg[(size_t)cur * D + col], a);
                cur = d; a = 0.f;
            }
            a += sMsg[(rbase + i) * 132 + col];
        }
        atomicAdd(&agg[(size_t)cur * D + col], a);
    }
}

// ---------------- node update + residual + LayerNorm ----------------
__global__ __launch_bounds__(256, 3) void node_mfma_kernel(
    const float* __restrict__ hidden, const u16* __restrict__ hbf,
    const float* __restrict__ agg,
    const u16* __restrict__ W1T, const float* __restrict__ b1,
    const u16* __restrict__ W2T, const float* __restrict__ b2,
    const float* __restrict__ gamma, const float* __restrict__ beta,
    float* __restrict__ hidden_out, u16* __restrict__ hbf_out)
{
    __shared__ u16 sA[64 * 264];
    __shared__ u16 sH1[64 * 136];
    float* sR = (float*)sA;
    const int tid = threadIdx.x;
    const int n0 = blockIdx.x * 64;

    {
        const int e = tid >> 2, q = tid & 3;
        int n = n0 + e; if (n >= NN) n = NN - 1;
        const uint4* hs = (const uint4*)(hbf + (size_t)n * D);
        const float4* ag = (const float4*)(agg + (size_t)n * D);
        uint4* ar = (uint4*)(sA + e * 264);
#pragma unroll
        for (int c = 0; c < 8; ++c) {
            int cc = q * 8 + c;
            if (cc < 16) ar[cc] = hs[cc];
            else {
                float4 x0 = ag[(cc - 16) * 2];
                float4 x1 = ag[(cc - 16) * 2 + 1];
                uint4 p;
                p.x = (unsigned)f2bf(x0.x) | ((unsigned)f2bf(x0.y) << 16);
                p.y = (unsigned)f2bf(x0.z) | ((unsigned)f2bf(x0.w) << 16);
                p.z = (unsigned)f2bf(x1.x) | ((unsigned)f2bf(x1.y) << 16);
                p.w = (unsigned)f2bf(x1.z) | ((unsigned)f2bf(x1.w) << 16);
                ar[cc] = p;
            }
        }
    }
    __syncthreads();

    const int lane = tid & 63;
    const int l15 = lane & 15;
    const int quad = lane >> 4;
    const int nbase = (tid >> 6) * 32;

    f32x4 acc[4][2];
#pragma unroll
    for (int mt = 0; mt < 4; ++mt)
#pragma unroll
        for (int nt = 0; nt < 2; ++nt) acc[mt][nt] = (f32x4){0.f, 0.f, 0.f, 0.f};

    const u16* bp0 = W1T + (size_t)(nbase + l15) * 256 + quad * 8;
    const u16* bp1 = bp0 + 16 * 256;
#pragma unroll
    for (int kb = 0; kb < 256; kb += 32) {
        bf16x8 bf0 = *(const bf16x8*)(bp0 + kb);
        bf16x8 bf1 = *(const bf16x8*)(bp1 + kb);
#pragma unroll
        for (int mt = 0; mt < 4; ++mt) {
            bf16x8 af = *(const bf16x8*)(sA + (mt * 16 + l15) * 264 + quad * 8 + kb);
            acc[mt][0] = __builtin_amdgcn_mfma_f32_16x16x32_bf16(af, bf0, acc[mt][0], 0, 0, 0);
            acc[mt][1] = __builtin_amdgcn_mfma_f32_16x16x32_bf16(af, bf1, acc[mt][1], 0, 0, 0);
        }
    }

#pragma unroll
    for (int mt = 0; mt < 4; ++mt)
#pragma unroll
        for (int nt = 0; nt < 2; ++nt) {
            const int col = nbase + nt * 16 + l15;
            const float bb = b1[col];
#pragma unroll
            for (int r = 0; r < 4; ++r) {
                const int row = mt * 16 + quad * 4 + r;
                sH1[row * 136 + col] = f2bf(gelu_f(acc[mt][nt][r] + bb));
            }
        }
    __syncthreads();

    f32x4 acc2[4][2];
#pragma unroll
    for (int mt = 0; mt < 4; ++mt)
#pragma unroll
        for (int nt = 0; nt < 2; ++nt) acc2[mt][nt] = (f32x4){0.f, 0.f, 0.f, 0.f};

    const u16* cp0 = W2T + (size_t)(nbase + l15) * 128 + quad * 8;
    const u16* cp1 = cp0 + 16 * 128;
#pragma unroll
    for (int kb = 0; kb < 128; kb += 32) {
        bf16x8 bf0 = *(const bf16x8*)(cp0 + kb);
        bf16x8 bf1 = *(const bf16x8*)(cp1 + kb);
#pragma unroll
        for (int mt = 0; mt < 4; ++mt) {
            bf16x8 af = *(const bf16x8*)(sH1 + (mt * 16 + l15) * 136 + quad * 8 + kb);
            acc2[mt][0] = __builtin_amdgcn_mfma_f32_16x16x32_bf16(af, bf0, acc2[mt][0], 0, 0, 0);
            acc2[mt][1] = __builtin_amdgcn_mfma_f32_16x16x32_bf16(af, bf1, acc2[mt][1], 0, 0, 0);
        }
    }

#pragma unroll
    for (int mt = 0; mt < 4; ++mt)
#pragma unroll
        for (int nt = 0; nt < 2; ++nt) {
            const int col = nbase + nt * 16 + l15;
            const float bb = b2[col];
#pragma unroll
            for (int r = 0; r < 4; ++r) {
                const int row = mt * 16 + quad * 4 + r;
                int n = n0 + row; if (n >= NN) n = NN - 1;
                sR[row * 132 + col] = acc2[mt][nt][r] + bb + hidden[(size_t)n * D + col];
            }
        }
    __syncthreads();

    {
        const int e = tid >> 2, t4 = tid & 3;
        const int n = n0 + e;
        const float* rr = sR + e * 132 + t4 * 32;
        float s1 = 0.f, s2 = 0.f;
        float4 v[8];
#pragma unroll
        for (int i = 0; i < 8; ++i) {
            v[i] = *(const float4*)(rr + i * 4);
            s1 += v[i].x + v[i].y + v[i].z + v[i].w;
            s2 += v[i].x * v[i].x + v[i].y * v[i].y + v[i].z * v[i].z + v[i].w * v[i].w;
        }
        s1 += __shfl_xor(s1, 1); s2 += __shfl_xor(s2, 1);
        s1 += __shfl_xor(s1, 2); s2 += __shfl_xor(s2, 2);
        const float mean = s1 * (1.f / 128.f);
        const float var = s2 * (1.f / 128.f) - mean * mean;
        const float rs = rsqrtf(var + LN_EPS);
        if (n < NN) {
            float* op = hidden_out + (size_t)n * D + t4 * 32;
            u16* bp = hbf_out + (size_t)n * D + t4 * 32;
#pragma unroll
            for (int i = 0; i < 8; ++i) {
                const float4 g = *(const float4*)(gamma + t4 * 32 + i * 4);
                const float4 be = *(const float4*)(beta + t4 * 32 + i * 4);
                float4 o;
                o.x = (v[i].x - mean) * rs * g.x + be.x;
                o.y = (v[i].y - mean) * rs * g.y + be.y;
                o.z = (v[i].z - mean) * rs * g.z + be.z;
                o.w = (v[i].w - mean) * rs * g.w + be.w;
                *(float4*)(op + i * 4) = o;
                uint2 pk;
                pk.x = (unsigned)f2bf(o.x) | ((unsigned)f2bf(o.y) << 16);
                pk.y = (unsigned)f2bf(o.z) | ((unsigned)f2bf(o.w) << 16);
                *(uint2*)(bp + i * 4) = pk;
            }
        }
    }
}

// ---------------- pooling ----------------
__global__ __launch_bounds__(256) void count_kernel(
    const int* __restrict__ batch, float* __restrict__ counts)
{
    int t = blockIdx.x * 256 + threadIdx.x;
    const int chunk = (NN + 8191) / 8192;
    int beg = t * chunk, end = beg + chunk;
    if (end > NN) end = NN;
    if (beg >= NN) return;
    int cur = batch[beg];
    float cnt = 0.f;
    for (int i = beg; i < end; ++i) {
        int b = batch[i];
        if (b != cur) { atomicAdd(&counts[cur], cnt); cur = b; cnt = 0.f; }
        cnt += 1.f;
    }
    atomicAdd(&counts[cur], cnt);
}

__global__ __launch_bounds__(256) void pool_accum_kernel(
    const float* __restrict__ hidden, const int* __restrict__ batch,
    float* __restrict__ pooled)
{
    __shared__ int sb[128];
    const int n0 = blockIdx.x * 128;
    const int tid = threadIdx.x;
    if (tid < 128) sb[tid] = (n0 + tid < NN) ? batch[n0 + tid] : -1;
    __syncthreads();
    const int col = tid & 127, half = tid >> 7;
    const int base = half * 64;
    int cur = sb[base];
    float acc = 0.f;
    for (int i = 0; i < 64; ++i) {
        int n = n0 + base + i;
        if (n >= NN) break;
        int b = sb[base + i];
        if (b != cur) { atomicAdd(&pooled[cur * D + col], acc); cur = b; acc = 0.f; }
        acc += hidden[(size_t)n * D + col];
    }
    if (cur >= 0 && acc != 0.f) atomicAdd(&pooled[cur * D + col], acc);
}

__global__ __launch_bounds__(256) void pool_div_kernel(
    float* __restrict__ pooled, const float* __restrict__ counts)
{
    int i = blockIdx.x * 256 + threadIdx.x;
    pooled[i] /= fmaxf(counts[i >> 7], 1.0f);
}

extern "C" void kernel_launch(void* const* d_in, const int* in_sizes, int n_in,
                              void* d_out, int out_size, void* d_ws, size_t ws_size,
                              hipStream_t stream) {
    const float* X     = (const float*)d_in[0];
    const int*   eidx  = (const int*)d_in[1];
    const float* ew    = (const float*)d_in[2];
    const int*   batch = (const int*)d_in[3];
    const float* W_in  = (const float*)d_in[5];
    const float* b_in  = (const float*)d_in[6];
    const float* eW1   = (const float*)d_in[7];
    const float* eb1   = (const float*)d_in[8];
    const float* eW2   = (const float*)d_in[9];
    const float* eb2   = (const float*)d_in[10];
    const float* uW1   = (const float*)d_in[11];
    const float* ub1   = (const float*)d_in[12];
    const float* uW2   = (const float*)d_in[13];
    const float* ub2   = (const float*)d_in[14];
    const float* gamma = (const float*)d_in[15];
    const float* beta  = (const float*)d_in[16];

    float* out_hidden = (float*)d_out;
    float* out_pooled = out_hidden + (size_t)NN * D;

    float* hA   = (float*)d_ws;                                // 25.6 MB
    float* agg  = hA + (size_t)NN * D;                         // 25.6 MB
    u16*   hbf  = (u16*)(agg + (size_t)NN * D);                // 12.8 MB
    u16*   eW1T = hbf + (size_t)NN * D;
    u16*   eW2T = eW1T + (size_t)NL * 128 * 256;
    u16*   uW1T = eW2T + (size_t)NL * 128 * 128;
    u16*   uW2T = uW1T + (size_t)NL * 128 * 256;
    int*   hist   = (int*)(uW2T + (size_t)NL * 128 * 128);     // NN ints
    int*   cursor = hist + NN;                                 // NN ints
    int*   sSrc   = cursor + NN;                               // NE ints
    int*   sDst   = sSrc + NE;                                 // NE ints
    float* sEw    = (float*)(sDst + NE);                       // NE floats
    float* counts = sEw + NE;                                  // NG floats

    const int* src = eidx;
    const int* dst = eidx + NE;

    // --- edge sort by dst (counting sort) ---
    hipMemsetAsync(hist, 0, (size_t)NN * sizeof(int), stream);
    hist_kernel<<<NE / 256, 256, 0, stream>>>(dst, hist);
    scan_kernel<<<1, 1024, 0, stream>>>(hist, cursor);
    scatter_kernel<<<NE / 256, 256, 0, stream>>>(src, dst, ew, cursor, sSrc, sDst, sEw);

    // --- weight prep + input projection ---
    transpose_cvt_kernel<<<384, 256, 0, stream>>>(eW1, eW1T, 256, 128, 257 * 128, 128 * 256);
    transpose_cvt_kernel<<<192, 256, 0, stream>>>(eW2, eW2T, 128, 128, 128 * 128, 128 * 128);
    transpose_cvt_kernel<<<384, 256, 0, stream>>>(uW1, uW1T, 256, 128, 256 * 128, 128 * 256);
    transpose_cvt_kernel<<<192, 256, 0, stream>>>(uW2, uW2T, 128, 128, 128 * 128, 128 * 128);
    input_proj_kernel<<<(NN * D) / 256, 256, 0, stream>>>(X, W_in, b_in, hA, hbf);

    const float* hin = hA;
    for (int l = 0; l < NL; ++l) {
        hipMemsetAsync(agg, 0, (size_t)NN * D * sizeof(float), stream);
        edge_mfma_kernel<<<NE / 64, 256, 0, stream>>>(
            hbf, sSrc, sDst, sEw,
            eW1T + (size_t)l * 128 * 256,
            eW1 + (size_t)l * 257 * 128 + 256 * 128,
            eb1 + (size_t)l * D,
            eW2T + (size_t)l * 128 * 128, eb2 + (size_t)l * D, agg);
        float* hout = (l & 1) ? hA : out_hidden;
        node_mfma_kernel<<<(NN + 63) / 64, 256, 0, stream>>>(
            hin, hbf, agg,
            uW1T + (size_t)l * 128 * 256, ub1 + (size_t)l * D,
            uW2T + (size_t)l * 128 * 128, ub2 + (size_t)l * D,
            gamma + (size_t)l * D, beta + (size_t)l * D,
            hout, hbf);
        hin = hout;
    }

    hipMemsetAsync(out_pooled, 0, (size_t)NG * D * sizeof(float), stream);
    hipMemsetAsync(counts, 0, (size_t)NG * sizeof(float), stream);
    count_kernel<<<32, 256, 0, stream>>>(batch, counts);
    pool_accum_kernel<<<(NN + 127) / 128, 256, 0, stream>>>(out_hidden, batch, out_pooled);
    pool_div_kernel<<<(NG * D) / 256, 256, 0, stream>>>(out_pooled, counts);
}